// Round 16
// baseline (172.531 us; speedup 1.0000x reference)
//
#include <hip/hip_runtime.h>

typedef _Float16 f16x8 __attribute__((ext_vector_type(8)));
using f32x4 = __attribute__((ext_vector_type(4))) float;

constexpr int B = 64, L = 256, D = 1024;
constexpr int BD = B * D;          // 65536
constexpr float EPS = 1e-6f;

__device__ __forceinline__ void gload_lds16(const void* g, void* l) {
    __builtin_amdgcn_global_load_lds((const __attribute__((address_space(1))) void*)g,
                                     (__attribute__((address_space(3))) void*)l,
                                     16, 0, 0);
}

// ---------------------------------------------------------------------------
// WF transpose->fp16 (blocks [0,1024)) + gp partials (blocks [1024,1088))
// ---------------------------------------------------------------------------
__global__ __launch_bounds__(256) void k_wfgp(const float* __restrict__ WF,
                                              const float* __restrict__ WG,
                                              const float* __restrict__ WH,
                                              short* __restrict__ WFt16,
                                              float* __restrict__ gp1,
                                              float* __restrict__ gp2) {
    __shared__ float tile[32][33];
    const int bid = blockIdx.x;
    if (bid < 1024) {
        const int rt = bid >> 5, ct = bid & 31;
        const int t = threadIdx.x;
        const int r = t >> 3, c4 = (t & 7) * 4;
        float4 v = *(const float4*)(WF + (long)(rt * 32 + r) * D + ct * 32 + c4);
        tile[r][c4] = v.x; tile[r][c4 + 1] = v.y; tile[r][c4 + 2] = v.z; tile[r][c4 + 3] = v.w;
        __syncthreads();
        union { _Float16 h[4]; short4 s; } u;
        u.h[0] = (_Float16)tile[c4 + 0][r];
        u.h[1] = (_Float16)tile[c4 + 1][r];
        u.h[2] = (_Float16)tile[c4 + 2][r];
        u.h[3] = (_Float16)tile[c4 + 3][r];
        *(short4*)(WFt16 + (long)(ct * 32 + r) * D + rt * 32 + c4) = u.s;
    } else {
        const int lb = bid - 1024;                    // 0..63
        const int kx = lb & 7, ec = lb >> 3;
        const int k = kx * 256 + threadIdx.x;         // 0..2047
        const int e0 = ec * 128;
        float a = 0.f, c = 0.f;
        for (int e = 0; e < 128; ++e) {
            float w = WG[(long)(e0 + e) * (2 * D) + k];
            a += w * WH[e0 + e];
            c += w * WH[D + e0 + e];
        }
        gp1[ec * 2048 + k] = a; gp2[ec * 2048 + k] = c;
    }
}

// ---------------------------------------------------------------------------
// k_qG8: T16 = q(fp32) @ G16^T. Phase-split counted-vmcnt pipeline (T3+T4+T5).
// 256x128 tile, BK=64, 8 waves (4M x 2N, 64x64/wave, acc[4][4]).
// 3 LDS buffers (48 KB each: A 256x64 fp16 + B 128x64 fp16).
// Iter kt: ph0 { issue kt+2 stages (2 B gloads + 8 A f32 loads) ; ds_read
// khalf0 ; setprio MFMA16 } barrier ; ph1 { ds_read khalf1 ; MFMA16 ;
// cvt+ds_write A(kt+1) (regs from iter kt-1) ; lgkm(0) ; vmcnt(10) = keep
// kt+2's 10 ops in flight, everything older complete } barrier.
// Swizzle: LDS slot (row,s) holds global granule s^(row&7) (R14-verified).
// ---------------------------------------------------------------------------
__global__ __launch_bounds__(512, 1) void k_qG8(const char* __restrict__ Aq,
                                                const char* __restrict__ Bg,
                                                short* __restrict__ Ch) {
    constexpr int TILEB = 49152;                 // 32 KB A + 16 KB B
    __shared__ __align__(16) char lds[3 * TILEB];
    const int t = threadIdx.x, lane = t & 63, w = t >> 6;
    const int wm = w >> 1, wn = w & 1;

    // XCD-bijective swizzle, grid 512 (64 m-tiles x 8 n-tiles)
    const int lin = blockIdx.x;
    const int swz = (lin & 7) * 64 + (lin >> 3);
    const int mb = (swz >> 3) * 256, nb = (swz & 7) * 128;

    // A stage: 4 rounds x (2 float4) fp32; row = (r*512+t)>>3, sg = &7
    const char* spA[4];
    #pragma unroll
    for (int r = 0; r < 4; ++r) {
        int g = r * 512 + t;
        int row = g >> 3, sg = g & 7;
        spA[r] = Aq + (long)(mb + row) * 4096 + (sg ^ (row & 7)) * 32;
    }
    // B stage: 2 rounds gload_lds; row = (r*512+t)>>3 (0..127)
    const char* spB[2];
    #pragma unroll
    for (int r = 0; r < 2; ++r) {
        int g = r * 512 + t;
        int row = g >> 3, sg = g & 7;
        spB[r] = Bg + (long)(nb + row) * 2048 + (sg ^ (row & 7)) * 16;
    }

    // fragment offsets per k-half
    int aoff[4][2], boff[4][2];
    #pragma unroll
    for (int i = 0; i < 4; ++i) {
        int ra = wm * 64 + i * 16 + (lane & 15);
        #pragma unroll
        for (int kh = 0; kh < 2; ++kh) {
            int c = (lane >> 4) + 4 * kh;
            aoff[i][kh] = ra * 128 + ((c ^ (ra & 7))) * 16;
        }
    }
    #pragma unroll
    for (int j = 0; j < 4; ++j) {
        int rb = wn * 64 + j * 16 + (lane & 15);
        #pragma unroll
        for (int kh = 0; kh < 2; ++kh) {
            int c = (lane >> 4) + 4 * kh;
            boff[j][kh] = 32768 + rb * 128 + ((c ^ (rb & 7))) * 16;
        }
    }

    f32x4 acc[4][4] = {};
    constexpr int NT = 16;
    float4 rsE[4][2], rsO[4][2];

#define QG_LOADA(KT, RS)                                                    \
    {                                                                       \
        long kb = (long)(KT) * 256;                                         \
        _Pragma("unroll")                                                   \
        for (int r = 0; r < 4; ++r) {                                       \
            RS[r][0] = *(const float4*)(spA[r] + kb);                       \
            RS[r][1] = *(const float4*)(spA[r] + kb + 16);                  \
        }                                                                   \
    }
#define QG_LOADB(KT)                                                        \
    {                                                                       \
        long kb = (long)(KT) * 128;                                         \
        char* dstb = lds + ((KT) % 3) * TILEB + 32768;                      \
        _Pragma("unroll")                                                   \
        for (int r = 0; r < 2; ++r)                                         \
            gload_lds16(spB[r] + kb, dstb + (r * 512 + t) * 16);            \
    }
#define QG_WRITEA(KT, RS)                                                   \
    {                                                                       \
        char* dstb = lds + ((KT) % 3) * TILEB;                              \
        _Pragma("unroll")                                                   \
        for (int r = 0; r < 4; ++r) {                                       \
            union { _Float16 h[8]; int4 v; } u;                             \
            float4 s0 = RS[r][0], s1 = RS[r][1];                            \
            u.h[0]=(_Float16)s0.x; u.h[1]=(_Float16)s0.y;                   \
            u.h[2]=(_Float16)s0.z; u.h[3]=(_Float16)s0.w;                   \
            u.h[4]=(_Float16)s1.x; u.h[5]=(_Float16)s1.y;                   \
            u.h[6]=(_Float16)s1.z; u.h[7]=(_Float16)s1.w;                   \
            *((int4*)(dstb + (r * 512 + t) * 16)) = u.v;                    \
        }                                                                   \
    }
#define QG_MFMA(KT, KH)                                                     \
    {                                                                       \
        const char* lb = lds + ((KT) % 3) * TILEB;                          \
        f16x8 fb[4], fa[4];                                                 \
        _Pragma("unroll")                                                   \
        for (int j = 0; j < 4; ++j) fb[j] = *(const f16x8*)(lb + boff[j][KH]); \
        _Pragma("unroll")                                                   \
        for (int i = 0; i < 4; ++i) fa[i] = *(const f16x8*)(lb + aoff[i][KH]); \
        __builtin_amdgcn_s_setprio(1);                                      \
        _Pragma("unroll")                                                   \
        for (int i = 0; i < 4; ++i)                                         \
            _Pragma("unroll")                                               \
            for (int j = 0; j < 4; ++j)                                     \
                acc[i][j] = __builtin_amdgcn_mfma_f32_16x16x32_f16(         \
                    fb[j], fa[i], acc[i][j], 0, 0, 0);                      \
        __builtin_amdgcn_s_setprio(0);                                      \
    }
#define QG_ITER(KT, RSLOAD, RSWRITE)                                        \
    {                                                                       \
        /* ph0 */                                                           \
        if ((KT) + 2 < NT) { QG_LOADB((KT) + 2) QG_LOADA((KT) + 2, RSLOAD) }\
        QG_MFMA(KT, 0)                                                      \
        __builtin_amdgcn_s_barrier();                                       \
        /* ph1 */                                                           \
        QG_MFMA(KT, 1)                                                      \
        if ((KT) + 1 < NT) {                                                \
            QG_WRITEA((KT) + 1, RSWRITE)                                    \
            asm volatile("s_waitcnt lgkmcnt(0)" ::: "memory");              \
        }                                                                   \
        if ((KT) + 2 < NT)                                                  \
            asm volatile("s_waitcnt vmcnt(10)" ::: "memory");               \
        else                                                                \
            asm volatile("s_waitcnt vmcnt(0)" ::: "memory");                \
        __builtin_amdgcn_s_barrier();                                       \
    }

    // prologue: tile 0 fully staged; tile 1 issued (A in rsO)
    QG_LOADB(0)
    QG_LOADA(0, rsE)
    QG_WRITEA(0, rsE)                  // dataflow-waits the A0 loads
    QG_LOADB(1)
    QG_LOADA(1, rsO)
    asm volatile("s_waitcnt lgkmcnt(0)" ::: "memory");
    asm volatile("s_waitcnt vmcnt(10)" ::: "memory");   // B0 done; tile1 in flight
    __builtin_amdgcn_s_barrier();

    for (int kt = 0; kt < NT; kt += 2) {
        QG_ITER(kt, rsE, rsO)          // even: load kt+2 -> rsE, write A(kt+1) from rsO
        QG_ITER(kt + 1, rsO, rsE)      // odd:  load kt+3 -> rsO, write A(kt+2) from rsE
    }
#undef QG_ITER
#undef QG_MFMA
#undef QG_WRITEA
#undef QG_LOADB
#undef QG_LOADA

    // epilogue
    #pragma unroll
    for (int i = 0; i < 4; ++i)
        #pragma unroll
        for (int j = 0; j < 4; ++j) {
            int row = mb + wm * 64 + i * 16 + (lane & 15);
            int col = nb + wn * 64 + j * 16 + (lane >> 4) * 4;
            union { _Float16 h[4]; short4 s; } u;
            #pragma unroll
            for (int rr = 0; rr < 4; ++rr) u.h[rr] = (_Float16)acc[i][j][rr];
            *(short4*)(Ch + (long)row * 1024 + col) = u.s;
        }
}

// ---------------------------------------------------------------------------
// fp16 NT GEMM (R14/R15 template) for gram + E.
// ---------------------------------------------------------------------------
template <int WM, int WN, int MR, int A32, int B32>
__global__ __launch_bounds__(WM * WN * 64) void k_gemm(
    const char* __restrict__ A, long sA, long bA,
    const char* __restrict__ Bm, long sB, long bB,
    int K, int bx, int per_batch, int f16_out,
    short* __restrict__ Ch, float* __restrict__ Cf, int ldC, long batchC)
{
    constexpr int BM = WM * MR * 16, BN = WN * 64;
    constexpr int T = WM * WN * 64;
    constexpr int TILEB = (BM + BN) * 128;       // fp16 bytes per BK=64 buffer
    constexpr int ROUNDS = TILEB / (T * 16);
    constexpr int ROUNDS_A = (BM * 128) / (T * 16);
    constexpr int R0 = A32 ? 0 : ROUNDS_A;
    constexpr int R1 = A32 ? ROUNDS_A : (B32 ? ROUNDS : ROUNDS_A);
    constexpr int NRS = (R1 > R0) ? (R1 - R0) : 1;
    __shared__ __align__(16) char lds[2 * TILEB];

    const int t = threadIdx.x, lane = t & 63, w = t >> 6;
    const int wm = w / WN, wn = w % WN;

    const int lin = blockIdx.x;
    const int chunk = gridDim.x >> 3;
    const int swz = (lin & 7) * chunk + (lin >> 3);
    const int z = swz / per_batch;
    const int r0_ = swz % per_batch;
    const int mb = (r0_ / bx) * BM, nb = (r0_ % bx) * BN;

    const char* Ab = A + bA * z;
    const char* Bb = Bm + bB * z;

    const char* sp[ROUNDS];
    #pragma unroll
    for (int r = 0; r < ROUNDS; ++r) {
        int g = r * T + t;
        int row = g >> 3, sg = g & 7;
        int lg = sg ^ (row & 7);
        if (r < ROUNDS_A) sp[r] = Ab + (long)(mb + row) * sA + lg * (A32 ? 32 : 16);
        else              sp[r] = Bb + (long)(nb + row - BM) * sB + lg * (B32 ? 32 : 16);
    }

    int aoff[MR][2], boff[4][2];
    #pragma unroll
    for (int i = 0; i < MR; ++i) {
        int ra = wm * (MR * 16) + i * 16 + (lane & 15);
        #pragma unroll
        for (int kh = 0; kh < 2; ++kh) {
            int c = (lane >> 4) + 4 * kh;
            aoff[i][kh] = ra * 128 + (c ^ (ra & 7)) * 16;
        }
    }
    #pragma unroll
    for (int j = 0; j < 4; ++j) {
        int rb = wn * 64 + j * 16 + (lane & 15);
        #pragma unroll
        for (int kh = 0; kh < 2; ++kh) {
            int c = (lane >> 4) + 4 * kh;
            boff[j][kh] = BM * 128 + rb * 128 + (c ^ (rb & 7)) * 16;
        }
    }

    f32x4 acc[MR][4] = {};
    const int NT = K >> 6;

    {   // prologue: stage K-tile 0 into buf 0
        #pragma unroll
        for (int r = 0; r < ROUNDS; ++r) {
            const bool is32 = (r < ROUNDS_A) ? (A32 != 0) : (B32 != 0);
            if (is32) {
                float4 s0 = *(const float4*)(sp[r]);
                float4 s1 = *(const float4*)(sp[r] + 16);
                union { _Float16 h[8]; int4 v; } u;
                u.h[0]=(_Float16)s0.x; u.h[1]=(_Float16)s0.y; u.h[2]=(_Float16)s0.z; u.h[3]=(_Float16)s0.w;
                u.h[4]=(_Float16)s1.x; u.h[5]=(_Float16)s1.y; u.h[6]=(_Float16)s1.z; u.h[7]=(_Float16)s1.w;
                *((int4*)(lds + (r * T + t) * 16)) = u.v;
            } else {
                gload_lds16(sp[r], lds + (r * T + t) * 16);
            }
        }
        asm volatile("s_waitcnt lgkmcnt(0)" ::: "memory");
    }

    int cur = 0;
    for (int kt = 0; kt < NT; ++kt) {
        asm volatile("s_waitcnt vmcnt(0)" ::: "memory");
        __builtin_amdgcn_s_barrier();
        float4 stg[NRS][2];
        char* dstb = lds + (cur ^ 1) * TILEB;
        if (kt + 1 < NT) {
            #pragma unroll
            for (int r = 0; r < ROUNDS; ++r) {
                const bool is32 = (r < ROUNDS_A) ? (A32 != 0) : (B32 != 0);
                if (is32) {
                    long kb = (long)(kt + 1) * 256;
                    stg[r - R0][0] = *(const float4*)(sp[r] + kb);
                    stg[r - R0][1] = *(const float4*)(sp[r] + kb + 16);
                } else {
                    long kb = (long)(kt + 1) * 128;
                    gload_lds16(sp[r] + kb, dstb + (r * T + t) * 16);
                }
            }
        }
        const char* lb = lds + cur * TILEB;
        #pragma unroll
        for (int kh = 0; kh < 2; ++kh) {
            f16x8 fb[4], fa[MR];
            #pragma unroll
            for (int j = 0; j < 4; ++j) fb[j] = *(const f16x8*)(lb + boff[j][kh]);
            #pragma unroll
            for (int i = 0; i < MR; ++i) fa[i] = *(const f16x8*)(lb + aoff[i][kh]);
            #pragma unroll
            for (int i = 0; i < MR; ++i)
                #pragma unroll
                for (int j = 0; j < 4; ++j)
                    acc[i][j] = __builtin_amdgcn_mfma_f32_16x16x32_f16(fb[j], fa[i], acc[i][j], 0, 0, 0);
        }
        if ((A32 || B32) && (kt + 1 < NT)) {
            #pragma unroll
            for (int r = R0; r < R1; ++r) {
                union { _Float16 h[8]; int4 v; } u;
                float4 s0 = stg[r - R0][0], s1 = stg[r - R0][1];
                u.h[0]=(_Float16)s0.x; u.h[1]=(_Float16)s0.y;
                u.h[2]=(_Float16)s0.z; u.h[3]=(_Float16)s0.w;
                u.h[4]=(_Float16)s1.x; u.h[5]=(_Float16)s1.y;
                u.h[6]=(_Float16)s1.z; u.h[7]=(_Float16)s1.w;
                *((int4*)(dstb + (r * T + t) * 16)) = u.v;
            }
            asm volatile("s_waitcnt lgkmcnt(0)" ::: "memory");
        }
        cur ^= 1;
    }

    const long zC = batchC * z;
    #pragma unroll
    for (int i = 0; i < MR; ++i)
        #pragma unroll
        for (int j = 0; j < 4; ++j) {
            int row = mb + wm * (MR * 16) + i * 16 + (lane & 15);
            int col = nb + wn * 64 + j * 16 + (lane >> 4) * 4;
            long idx = zC + (long)row * ldC + col;
            if (f16_out) {
                union { _Float16 h[4]; short4 s; } u;
                #pragma unroll
                for (int rr = 0; rr < 4; ++rr) u.h[rr] = (_Float16)acc[i][j][rr];
                *(short4*)(Ch + idx) = u.s;
            } else {
                float4 v = make_float4(acc[i][j][0], acc[i][j][1], acc[i][j][2], acc[i][j][3]);
                *(float4*)(Cf + idx) = v;
            }
        }
}

// ---------------------------------------------------------------------------
// fold 4 f32 gram partials -> f16 G
// ---------------------------------------------------------------------------
__global__ __launch_bounds__(256) void k_fold_g(const float* __restrict__ Gp,
                                                short* __restrict__ G16) {
    const int i = blockIdx.x * 256 + threadIdx.x;    // float4 index
    constexpr int N4 = (1 << 20) / 4;
    const float4* g = (const float4*)Gp;
    float4 v0 = g[i], v1 = g[N4 + i], v2 = g[2 * N4 + i], v3 = g[3 * N4 + i];
    union { _Float16 h[4]; short4 s; } u;
    u.h[0] = (_Float16)(v0.x + v1.x + v2.x + v3.x);
    u.h[1] = (_Float16)(v0.y + v1.y + v2.y + v3.y);
    u.h[2] = (_Float16)(v0.z + v1.z + v2.z + v3.z);
    u.h[3] = (_Float16)(v0.w + v1.w + v2.w + v3.w);
    ((short4*)G16)[i] = u.s;
}

// ---------------------------------------------------------------------------
// Tiled softmax pass 1 (verified R3)
// ---------------------------------------------------------------------------
__global__ __launch_bounds__(256) void k_pass1(const float* __restrict__ E,
                                               const int* __restrict__ qm,
                                               const int* __restrict__ pm,
                                               float* __restrict__ impart,
                                               float* __restrict__ ispart,
                                               float* __restrict__ cjpart) {
    const int qc = blockIdx.x, b = blockIdx.y;
    const int p = threadIdx.x, lane = p & 63, w = p >> 6;
    const int q0 = qc * 32;
    __shared__ float wred[32][4];
    __shared__ float rowmx[32], rowsm[32], qmv_s[32];
    if (p < 32) qmv_s[p] = (float)qm[b * L + q0 + p];
    __syncthreads();
    const float pmv = (float)pm[b * L + p];
    const float* eb = E + b * (L * L) + q0 * L + p;

    float xv[32];
    float im = -1e30f;
    #pragma unroll
    for (int r = 0; r < 32; ++r) {
        float mm = pmv * qmv_s[r];
        float x = eb[r * L] * mm;
        xv[r] = x;
        im = fmaxf(im, x);
        float v = x;
        #pragma unroll
        for (int o = 32; o; o >>= 1) v = fmaxf(v, __shfl_xor(v, o));
        if (lane == 0) wred[r][w] = v;
    }
    __syncthreads();
    if (p < 32) rowmx[p] = fmaxf(fmaxf(wred[p][0], wred[p][1]), fmaxf(wred[p][2], wred[p][3]));
    __syncthreads();
    float is = 0.f;
    #pragma unroll
    for (int r = 0; r < 32; ++r) {
        float mm = pmv * qmv_s[r];
        is += mm * __expf(xv[r] - im);
        float v = mm * __expf(xv[r] - rowmx[r]);
        #pragma unroll
        for (int o = 32; o; o >>= 1) v += __shfl_xor(v, o);
        if (lane == 0) wred[r][w] = v;
    }
    __syncthreads();
    if (p < 32) rowsm[p] = wred[p][0] + wred[p][1] + wred[p][2] + wred[p][3];
    __syncthreads();
    float cj = 0.f;
    #pragma unroll
    for (int r = 0; r < 32; ++r) {
        float mm = pmv * qmv_s[r];
        cj += mm * __expf(xv[r] - rowmx[r]) / (rowsm[r] + EPS);
    }
    const int o = (b * 8 + qc) * 256 + p;
    impart[o] = im; ispart[o] = is; cjpart[o] = cj;
}

__global__ __launch_bounds__(256) void k_combine(const float* __restrict__ impart,
                                                 const float* __restrict__ ispart,
                                                 const float* __restrict__ cjpart,
                                                 float* __restrict__ rmi,
                                                 float* __restrict__ rsi,
                                                 float* __restrict__ colj) {
    const int b = blockIdx.x, p = threadIdx.x;
    const int base = b * 8 * 256 + p;
    float m = -1e30f, s = 0.f, c = 0.f;
    #pragma unroll
    for (int k = 0; k < 8; ++k) m = fmaxf(m, impart[base + k * 256]);
    #pragma unroll
    for (int k = 0; k < 8; ++k) {
        s += ispart[base + k * 256] * __expf(impart[base + k * 256] - m);
        c += cjpart[base + k * 256];
    }
    rmi[b * L + p] = m; rsi[b * L + p] = s; colj[b * L + p] = c;
}

__global__ __launch_bounds__(256) void k_colsum_i(const float* __restrict__ E,
                                                  const int* __restrict__ qm,
                                                  const int* __restrict__ pm,
                                                  const float* __restrict__ rmaxi,
                                                  const float* __restrict__ rsumi,
                                                  float* __restrict__ coli) {
    const int wid = threadIdx.x >> 6, lane = threadIdx.x & 63;
    const int row = blockIdx.x * 4 + wid;        // row = b*256 + q
    const int b = row >> 8;
    const float qmv = (float)qm[row];
    const float* er = E + row * L;
    float acc = 0.f;
    #pragma unroll
    for (int i = 0; i < 4; ++i) {
        int pp = lane + 64 * i;
        float mm = qmv * (float)pm[b * L + pp];
        float x = er[pp] * mm;
        acc += mm * __expf(x - rmaxi[b * L + pp]) / (rsumi[b * L + pp] + EPS);
    }
    #pragma unroll
    for (int o = 32; o; o >>= 1) acc += __shfl_xor(acc, o);
    if (lane == 0) coli[row] = acc;
}

// ---------------------------------------------------------------------------
// per-batch sums over an l-chunk of 16, reading fp32 q/p. grid (16, B).
// ---------------------------------------------------------------------------
__global__ __launch_bounds__(128) void k_sums2(const float* __restrict__ Q,
                                               const float* __restrict__ P,
                                               const float* __restrict__ colj,
                                               const float* __restrict__ coli,
                                               float* __restrict__ pq,
                                               float* __restrict__ pp,
                                               float* __restrict__ pb,
                                               float* __restrict__ pa) {
    const int c = blockIdx.x, b = blockIdx.y, t = threadIdx.x;
    const int d0 = t * 8;
    float aq[8] = {}, ap[8] = {}, ab[8] = {}, aa[8] = {};
    for (int l = c * 16; l < c * 16 + 16; ++l) {
        const float* qp = Q + (long)l * BD + b * D + d0;
        const float* pp_ = P + (long)l * BD + b * D + d0;
        float4 q0 = *(const float4*)qp, q1 = *(const float4*)(qp + 4);
        float4 p0 = *(const float4*)pp_, p1 = *(const float4*)(pp_ + 4);
        float cj = colj[b * L + l], ci = coli[b * L + l];
        float qv[8] = {q0.x, q0.y, q0.z, q0.w, q1.x, q1.y, q1.z, q1.w};
        float pv[8] = {p0.x, p0.y, p0.z, p0.w, p1.x, p1.y, p1.z, p1.w};
        #pragma unroll
        for (int k = 0; k < 8; ++k) {
            aq[k] += qv[k]; ap[k] += pv[k]; ab[k] += cj * pv[k]; aa[k] += ci * qv[k];
        }
    }
    const long o = ((long)c * B + b) * D + d0;
    *(float4*)(pq + o) = make_float4(aq[0], aq[1], aq[2], aq[3]);
    *(float4*)(pq + o + 4) = make_float4(aq[4], aq[5], aq[6], aq[7]);
    *(float4*)(pp + o) = make_float4(ap[0], ap[1], ap[2], ap[3]);
    *(float4*)(pp + o + 4) = make_float4(ap[4], ap[5], ap[6], ap[7]);
    *(float4*)(pb + o) = make_float4(ab[0], ab[1], ab[2], ab[3]);
    *(float4*)(pb + o + 4) = make_float4(ab[4], ab[5], ab[6], ab[7]);
    *(float4*)(pa + o) = make_float4(aa[0], aa[1], aa[2], aa[3]);
    *(float4*)(pa + o + 4) = make_float4(aa[4], aa[5], aa[6], aa[7]);
}

__global__ __launch_bounds__(256) void k_final2(const float* __restrict__ pq,
                                                const float* __restrict__ pp,
                                                const float* __restrict__ pb,
                                                const float* __restrict__ pa,
                                                const float* __restrict__ gp1,
                                                const float* __restrict__ gp2,
                                                float* __restrict__ out) {
    const int b = blockIdx.x, t = threadIdx.x;
    float acc = 0.f;
    for (int d = t; d < D; d += 256) {
        float sq = 0.f, sp_ = 0.f, sb = 0.f, sa = 0.f;
        #pragma unroll
        for (int c2 = 0; c2 < 16; ++c2) {
            long o = ((long)c2 * B + b) * D + d;
            sq += pq[o]; sp_ += pp[o]; sb += pb[o]; sa += pa[o];
        }
        float g1d = 0.f, g1D = 0.f, g2d = 0.f, g2D = 0.f;
        #pragma unroll
        for (int ec = 0; ec < 8; ++ec) {
            g1d += gp1[ec * 2048 + d];     g1D += gp1[ec * 2048 + D + d];
            g2d += gp2[ec * 2048 + d];     g2D += gp2[ec * 2048 + D + d];
        }
        acc += sq * g1d + sb * g1D + sp_ * g2d + sa * g2D;
    }
    #pragma unroll
    for (int o = 32; o; o >>= 1) acc += __shfl_xor(acc, o);
    __shared__ float red[4];
    const int wid = t >> 6, lane = t & 63;
    if (lane == 0) red[wid] = acc;
    __syncthreads();
    if (t == 0) out[b] = red[0] + red[1] + red[2] + red[3];
}

// ---------------------------------------------------------------------------
extern "C" void kernel_launch(void* const* d_in, const int* in_sizes, int n_in,
                              void* d_out, int out_size, void* d_ws, size_t ws_size,
                              hipStream_t stream) {
    const float* q  = (const float*)d_in[0];
    const float* p  = (const float*)d_in[1];
    const int*   qm = (const int*)d_in[2];
    const int*   pm = (const int*)d_in[3];
    const float* WF = (const float*)d_in[4];
    const float* WG = (const float*)d_in[5];
    const float* WH = (const float*)d_in[6];
    float* out = (float*)d_out;

    // Workspace layout (~72 MB)
    char* wsb = (char*)d_ws;
    short* T16   = (short*)(wsb);                   // 32 MB
    short* WFt16 = (short*)(wsb + (32l << 20));     // 2 MB
    short* G16   = (short*)(wsb + (34l << 20));     // 2 MB
    float* Gp    = (float*)(wsb + (36l << 20));     // 16 MB (dead after fold)
    float* E     = (float*)(wsb + (36l << 20));     // 16 MB (overlays Gp)
    float* st    = (float*)(wsb + (52l << 20));
    const int BL = B * L;
    float* impart = st;                  float* ispart = impart + B * 8 * 256;
    float* cjpart = ispart + B * 8 * 256;
    float* rmi  = cjpart + B * 8 * 256;  float* rsi  = rmi + BL;
    float* colj = rsi + BL;              float* coli = colj + BL;
    float* pq   = coli + BL;             float* pp   = pq + 16 * BD;
    float* pb   = pp + 16 * BD;          float* pa   = pb + 16 * BD;
    float* gp1  = pa + 16 * BD;          float* gp2  = gp1 + 8 * 2048;

    // prep: WF transpose | gp partials
    k_wfgp<<<1088, 256, 0, stream>>>(WF, WG, WH, WFt16, gp1, gp2);
    // gram partials: K-split 4 (z = K-chunk of 256, NT=4), 128x128 tiles
    k_gemm<2, 2, 4, 0, 0><<<256, 256, 0, stream>>>(
        (const char*)WFt16, 2048, 512, (const char*)WFt16, 2048, 512,
        256, 8, 64, 0, nullptr, Gp, 1024, 1l << 20);
    k_fold_g<<<1024, 256, 0, stream>>>(Gp, G16);
    // T = q @ G: phase-split counted-vmcnt kernel, 256x128 tiles, grid 512.
    k_qG8<<<512, 512, 0, stream>>>((const char*)q, (const char*)G16, T16);
    // E[b] = T_b @ p_b^T: A = T16, B = p fp32 (in-staging cvt). NT=16.
    k_gemm<2, 2, 4, 0, 1><<<256, 256, 0, stream>>>(
        (const char*)T16, 64l * 2048, 2048, (const char*)p, 64l * 4096, 4096,
        1024, 2, 4, 0, nullptr, E, 256, 65536);
    // softmax
    k_pass1<<<dim3(8, B), 256, 0, stream>>>(E, qm, pm, impart, ispart, cjpart);
    k_combine<<<B, 256, 0, stream>>>(impart, ispart, cjpart, rmi, rsi, colj);
    k_colsum_i<<<BL / 4, 256, 0, stream>>>(E, qm, pm, rmi, rsi, coli);
    // per-batch sums (fp32 q/p), 1024 blocks
    k_sums2<<<dim3(16, B), 128, 0, stream>>>(q, p, colj, coli, pq, pp, pb, pa);
    // final
    k_final2<<<B, 256, 0, stream>>>(pq, pp, pb, pa, gp1, gp2, out);
}

// Round 17
// 158.745 us; speedup vs baseline: 1.0868x; 1.0868x over previous
//
#include <hip/hip_runtime.h>

typedef _Float16 f16x8 __attribute__((ext_vector_type(8)));
using f32x4 = __attribute__((ext_vector_type(4))) float;

constexpr int B = 64, L = 256, D = 1024;
constexpr int BD = B * D;          // 65536
constexpr float EPS = 1e-6f;

__device__ __forceinline__ void gload_lds16(const void* g, void* l) {
    __builtin_amdgcn_global_load_lds((const __attribute__((address_space(1))) void*)g,
                                     (__attribute__((address_space(3))) void*)l,
                                     16, 0, 0);
}

// ---------------------------------------------------------------------------
// WF transpose->fp16 (blocks [0,1024)) + gp partials (blocks [1024,1088))
// ---------------------------------------------------------------------------
__global__ __launch_bounds__(256) void k_wfgp(const float* __restrict__ WF,
                                              const float* __restrict__ WG,
                                              const float* __restrict__ WH,
                                              short* __restrict__ WFt16,
                                              float* __restrict__ gp1,
                                              float* __restrict__ gp2) {
    __shared__ float tile[32][33];
    const int bid = blockIdx.x;
    if (bid < 1024) {
        const int rt = bid >> 5, ct = bid & 31;
        const int t = threadIdx.x;
        const int r = t >> 3, c4 = (t & 7) * 4;
        float4 v = *(const float4*)(WF + (long)(rt * 32 + r) * D + ct * 32 + c4);
        tile[r][c4] = v.x; tile[r][c4 + 1] = v.y; tile[r][c4 + 2] = v.z; tile[r][c4 + 3] = v.w;
        __syncthreads();
        union { _Float16 h[4]; short4 s; } u;
        u.h[0] = (_Float16)tile[c4 + 0][r];
        u.h[1] = (_Float16)tile[c4 + 1][r];
        u.h[2] = (_Float16)tile[c4 + 2][r];
        u.h[3] = (_Float16)tile[c4 + 3][r];
        *(short4*)(WFt16 + (long)(ct * 32 + r) * D + rt * 32 + c4) = u.s;
    } else {
        const int lb = bid - 1024;                    // 0..63
        const int kx = lb & 7, ec = lb >> 3;
        const int k = kx * 256 + threadIdx.x;         // 0..2047
        const int e0 = ec * 128;
        float a = 0.f, c = 0.f;
        for (int e = 0; e < 128; ++e) {
            float w = WG[(long)(e0 + e) * (2 * D) + k];
            a += w * WH[e0 + e];
            c += w * WH[D + e0 + e];
        }
        gp1[ec * 2048 + k] = a; gp2[ec * 2048 + k] = c;
    }
}

// ---------------------------------------------------------------------------
// fp16 NT GEMM, BK=64 (R14 — best measured). 1-deep 2-buffer schedule:
// per K-step {vmcnt(0) -> barrier -> issue loads (fp16 gload_lds /
// fp32->regs) -> MFMA(2 k-halves) -> cvt+ds_write fp32 rounds -> lgkm(0)}.
// Rows are 8 granules (128B): swizzle lg = sg ^ (row&7); read uses the same
// involution -> 2-way (free) LDS banks. Linear gload_lds dest (rule #21).
// MFMA operands swapped -> acc reg-axis = output column -> vector C stores.
// ---------------------------------------------------------------------------
template <int WM, int WN, int MR, int A32, int B32>
__global__ __launch_bounds__(WM * WN * 64) void k_gemm(
    const char* __restrict__ A, long sA, long bA,
    const char* __restrict__ Bm, long sB, long bB,
    int K, int bx, int per_batch, int f16_out,
    short* __restrict__ Ch, float* __restrict__ Cf, int ldC, long batchC)
{
    constexpr int BM = WM * MR * 16, BN = WN * 64;
    constexpr int T = WM * WN * 64;
    constexpr int TILEB = (BM + BN) * 128;       // fp16 bytes per BK=64 buffer
    constexpr int ROUNDS = TILEB / (T * 16);
    constexpr int ROUNDS_A = (BM * 128) / (T * 16);
    constexpr int R0 = A32 ? 0 : ROUNDS_A;       // fp32 round range [R0,R1)
    constexpr int R1 = A32 ? ROUNDS_A : (B32 ? ROUNDS : ROUNDS_A);
    constexpr int NRS = (R1 > R0) ? (R1 - R0) : 1;
    __shared__ __align__(16) char lds[2 * TILEB];

    const int t = threadIdx.x, lane = t & 63, w = t >> 6;
    const int wm = w / WN, wn = w % WN;

    // XCD-bijective swizzle (grids divisible by 8)
    const int lin = blockIdx.x;
    const int chunk = gridDim.x >> 3;
    const int swz = (lin & 7) * chunk + (lin >> 3);
    const int z = swz / per_batch;
    const int r0_ = swz % per_batch;
    const int mb = (r0_ / bx) * BM, nb = (r0_ % bx) * BN;

    const char* Ab = A + bA * z;
    const char* Bb = Bm + bB * z;

    // stage source pointers: LDS slot g=(r*T+t) -> row g>>3, slot s=g&7
    // holds GLOBAL granule s^(row&7) of that row (32B granule when fp32)
    const char* sp[ROUNDS];
    #pragma unroll
    for (int r = 0; r < ROUNDS; ++r) {
        int g = r * T + t;
        int row = g >> 3, sg = g & 7;
        int lg = sg ^ (row & 7);
        if (r < ROUNDS_A) sp[r] = Ab + (long)(mb + row) * sA + lg * (A32 ? 32 : 16);
        else              sp[r] = Bb + (long)(nb + row - BM) * sB + lg * (B32 ? 32 : 16);
    }

    // fragment byte offsets, per k-half: want global granule c=(lane>>4)+4*kh
    // of row ra -> LDS slot c^(ra&7)
    int aoff[MR][2], boff[4][2];
    #pragma unroll
    for (int i = 0; i < MR; ++i) {
        int ra = wm * (MR * 16) + i * 16 + (lane & 15);
        #pragma unroll
        for (int kh = 0; kh < 2; ++kh) {
            int c = (lane >> 4) + 4 * kh;
            aoff[i][kh] = ra * 128 + (c ^ (ra & 7)) * 16;
        }
    }
    #pragma unroll
    for (int j = 0; j < 4; ++j) {
        int rb = wn * 64 + j * 16 + (lane & 15);
        #pragma unroll
        for (int kh = 0; kh < 2; ++kh) {
            int c = (lane >> 4) + 4 * kh;
            boff[j][kh] = BM * 128 + rb * 128 + (c ^ (rb & 7)) * 16;
        }
    }

    f32x4 acc[MR][4] = {};
    const int NT = K >> 6;

    {   // prologue: stage K-tile 0 into buf 0
        #pragma unroll
        for (int r = 0; r < ROUNDS; ++r) {
            const bool is32 = (r < ROUNDS_A) ? (A32 != 0) : (B32 != 0);
            if (is32) {
                float4 s0 = *(const float4*)(sp[r]);
                float4 s1 = *(const float4*)(sp[r] + 16);
                union { _Float16 h[8]; int4 v; } u;
                u.h[0]=(_Float16)s0.x; u.h[1]=(_Float16)s0.y; u.h[2]=(_Float16)s0.z; u.h[3]=(_Float16)s0.w;
                u.h[4]=(_Float16)s1.x; u.h[5]=(_Float16)s1.y; u.h[6]=(_Float16)s1.z; u.h[7]=(_Float16)s1.w;
                *((int4*)(lds + (r * T + t) * 16)) = u.v;
            } else {
                gload_lds16(sp[r], lds + (r * T + t) * 16);
            }
        }
        asm volatile("s_waitcnt lgkmcnt(0)" ::: "memory");
    }

    int cur = 0;
    for (int kt = 0; kt < NT; ++kt) {
        asm volatile("s_waitcnt vmcnt(0)" ::: "memory");
        __builtin_amdgcn_sched_barrier(0);
        __builtin_amdgcn_s_barrier();
        __builtin_amdgcn_sched_barrier(0);
        // issue next-tile loads: fp16 -> gload_lds direct; fp32 -> regs
        float4 stg[NRS][2];
        char* dstb = lds + (cur ^ 1) * TILEB;
        if (kt + 1 < NT) {
            #pragma unroll
            for (int r = 0; r < ROUNDS; ++r) {
                const bool is32 = (r < ROUNDS_A) ? (A32 != 0) : (B32 != 0);
                if (is32) {
                    long kb = (long)(kt + 1) * 256;
                    stg[r - R0][0] = *(const float4*)(sp[r] + kb);
                    stg[r - R0][1] = *(const float4*)(sp[r] + kb + 16);
                } else {
                    long kb = (long)(kt + 1) * 128;
                    gload_lds16(sp[r] + kb, dstb + (r * T + t) * 16);
                }
            }
        }
        __builtin_amdgcn_sched_barrier(0);
        // compute from buf[cur]: two k-halves of BK=64
        const char* lb = lds + cur * TILEB;
        #pragma unroll
        for (int kh = 0; kh < 2; ++kh) {
            f16x8 fb[4], fa[MR];
            #pragma unroll
            for (int j = 0; j < 4; ++j) fb[j] = *(const f16x8*)(lb + boff[j][kh]);
            #pragma unroll
            for (int i = 0; i < MR; ++i) fa[i] = *(const f16x8*)(lb + aoff[i][kh]);
            #pragma unroll
            for (int i = 0; i < MR; ++i)
                #pragma unroll
                for (int j = 0; j < 4; ++j)
                    acc[i][j] = __builtin_amdgcn_mfma_f32_16x16x32_f16(fb[j], fa[i], acc[i][j], 0, 0, 0);
        }
        // cvt + LDS-write the reg-staged fp32 rounds (compiler waits on stg)
        if ((A32 || B32) && (kt + 1 < NT)) {
            #pragma unroll
            for (int r = R0; r < R1; ++r) {
                union { _Float16 h[8]; int4 v; } u;
                float4 s0 = stg[r - R0][0], s1 = stg[r - R0][1];
                u.h[0]=(_Float16)s0.x; u.h[1]=(_Float16)s0.y;
                u.h[2]=(_Float16)s0.z; u.h[3]=(_Float16)s0.w;
                u.h[4]=(_Float16)s1.x; u.h[5]=(_Float16)s1.y;
                u.h[6]=(_Float16)s1.z; u.h[7]=(_Float16)s1.w;
                *((int4*)(dstb + (r * T + t) * 16)) = u.v;
            }
            asm volatile("s_waitcnt lgkmcnt(0)" ::: "memory");
            __builtin_amdgcn_sched_barrier(0);
        }
        cur ^= 1;
    }

    // epilogue: swapped mapping -> C-row = lane&15, C-col = (lane>>4)*4 + reg
    const long zC = batchC * z;
    #pragma unroll
    for (int i = 0; i < MR; ++i)
        #pragma unroll
        for (int j = 0; j < 4; ++j) {
            int row = mb + wm * (MR * 16) + i * 16 + (lane & 15);
            int col = nb + wn * 64 + j * 16 + (lane >> 4) * 4;
            long idx = zC + (long)row * ldC + col;
            if (f16_out) {
                union { _Float16 h[4]; short4 s; } u;
                #pragma unroll
                for (int rr = 0; rr < 4; ++rr) u.h[rr] = (_Float16)acc[i][j][rr];
                *(short4*)(Ch + idx) = u.s;
            } else {
                float4 v = make_float4(acc[i][j][0], acc[i][j][1], acc[i][j][2], acc[i][j][3]);
                *(float4*)(Cf + idx) = v;
            }
        }
}

// ---------------------------------------------------------------------------
// fold 4 f32 gram partials -> f16 G
// ---------------------------------------------------------------------------
__global__ __launch_bounds__(256) void k_fold_g(const float* __restrict__ Gp,
                                                short* __restrict__ G16) {
    const int i = blockIdx.x * 256 + threadIdx.x;    // float4 index
    constexpr int N4 = (1 << 20) / 4;
    const float4* g = (const float4*)Gp;
    float4 v0 = g[i], v1 = g[N4 + i], v2 = g[2 * N4 + i], v3 = g[3 * N4 + i];
    union { _Float16 h[4]; short4 s; } u;
    u.h[0] = (_Float16)(v0.x + v1.x + v2.x + v3.x);
    u.h[1] = (_Float16)(v0.y + v1.y + v2.y + v3.y);
    u.h[2] = (_Float16)(v0.z + v1.z + v2.z + v3.z);
    u.h[3] = (_Float16)(v0.w + v1.w + v2.w + v3.w);
    ((short4*)G16)[i] = u.s;
}

// ---------------------------------------------------------------------------
// Tiled softmax pass 1 (verified R3)
// ---------------------------------------------------------------------------
__global__ __launch_bounds__(256) void k_pass1(const float* __restrict__ E,
                                               const int* __restrict__ qm,
                                               const int* __restrict__ pm,
                                               float* __restrict__ impart,
                                               float* __restrict__ ispart,
                                               float* __restrict__ cjpart) {
    const int qc = blockIdx.x, b = blockIdx.y;
    const int p = threadIdx.x, lane = p & 63, w = p >> 6;
    const int q0 = qc * 32;
    __shared__ float wred[32][4];
    __shared__ float rowmx[32], rowsm[32], qmv_s[32];
    if (p < 32) qmv_s[p] = (float)qm[b * L + q0 + p];
    __syncthreads();
    const float pmv = (float)pm[b * L + p];
    const float* eb = E + b * (L * L) + q0 * L + p;

    float xv[32];
    float im = -1e30f;
    #pragma unroll
    for (int r = 0; r < 32; ++r) {
        float mm = pmv * qmv_s[r];
        float x = eb[r * L] * mm;
        xv[r] = x;
        im = fmaxf(im, x);
        float v = x;
        #pragma unroll
        for (int o = 32; o; o >>= 1) v = fmaxf(v, __shfl_xor(v, o));
        if (lane == 0) wred[r][w] = v;
    }
    __syncthreads();
    if (p < 32) rowmx[p] = fmaxf(fmaxf(wred[p][0], wred[p][1]), fmaxf(wred[p][2], wred[p][3]));
    __syncthreads();
    float is = 0.f;
    #pragma unroll
    for (int r = 0; r < 32; ++r) {
        float mm = pmv * qmv_s[r];
        is += mm * __expf(xv[r] - im);
        float v = mm * __expf(xv[r] - rowmx[r]);
        #pragma unroll
        for (int o = 32; o; o >>= 1) v += __shfl_xor(v, o);
        if (lane == 0) wred[r][w] = v;
    }
    __syncthreads();
    if (p < 32) rowsm[p] = wred[p][0] + wred[p][1] + wred[p][2] + wred[p][3];
    __syncthreads();
    float cj = 0.f;
    #pragma unroll
    for (int r = 0; r < 32; ++r) {
        float mm = pmv * qmv_s[r];
        cj += mm * __expf(xv[r] - rowmx[r]) / (rowsm[r] + EPS);
    }
    const int o = (b * 8 + qc) * 256 + p;
    impart[o] = im; ispart[o] = is; cjpart[o] = cj;
}

__global__ __launch_bounds__(256) void k_combine(const float* __restrict__ impart,
                                                 const float* __restrict__ ispart,
                                                 const float* __restrict__ cjpart,
                                                 float* __restrict__ rmi,
                                                 float* __restrict__ rsi,
                                                 float* __restrict__ colj) {
    const int b = blockIdx.x, p = threadIdx.x;
    const int base = b * 8 * 256 + p;
    float m = -1e30f, s = 0.f, c = 0.f;
    #pragma unroll
    for (int k = 0; k < 8; ++k) m = fmaxf(m, impart[base + k * 256]);
    #pragma unroll
    for (int k = 0; k < 8; ++k) {
        s += ispart[base + k * 256] * __expf(impart[base + k * 256] - m);
        c += cjpart[base + k * 256];
    }
    rmi[b * L + p] = m; rsi[b * L + p] = s; colj[b * L + p] = c;
}

__global__ __launch_bounds__(256) void k_colsum_i(const float* __restrict__ E,
                                                  const int* __restrict__ qm,
                                                  const int* __restrict__ pm,
                                                  const float* __restrict__ rmaxi,
                                                  const float* __restrict__ rsumi,
                                                  float* __restrict__ coli) {
    const int wid = threadIdx.x >> 6, lane = threadIdx.x & 63;
    const int row = blockIdx.x * 4 + wid;        // row = b*256 + q
    const int b = row >> 8;
    const float qmv = (float)qm[row];
    const float* er = E + row * L;
    float acc = 0.f;
    #pragma unroll
    for (int i = 0; i < 4; ++i) {
        int pp = lane + 64 * i;
        float mm = qmv * (float)pm[b * L + pp];
        float x = er[pp] * mm;
        acc += mm * __expf(x - rmaxi[b * L + pp]) / (rsumi[b * L + pp] + EPS);
    }
    #pragma unroll
    for (int o = 32; o; o >>= 1) acc += __shfl_xor(acc, o);
    if (lane == 0) coli[row] = acc;
}

// ---------------------------------------------------------------------------
// per-batch sums over an l-chunk of 16, reading fp32 q/p. grid (16, B).
// ---------------------------------------------------------------------------
__global__ __launch_bounds__(128) void k_sums2(const float* __restrict__ Q,
                                               const float* __restrict__ P,
                                               const float* __restrict__ colj,
                                               const float* __restrict__ coli,
                                               float* __restrict__ pq,
                                               float* __restrict__ pp,
                                               float* __restrict__ pb,
                                               float* __restrict__ pa) {
    const int c = blockIdx.x, b = blockIdx.y, t = threadIdx.x;
    const int d0 = t * 8;
    float aq[8] = {}, ap[8] = {}, ab[8] = {}, aa[8] = {};
    for (int l = c * 16; l < c * 16 + 16; ++l) {
        const float* qp = Q + (long)l * BD + b * D + d0;
        const float* pp_ = P + (long)l * BD + b * D + d0;
        float4 q0 = *(const float4*)qp, q1 = *(const float4*)(qp + 4);
        float4 p0 = *(const float4*)pp_, p1 = *(const float4*)(pp_ + 4);
        float cj = colj[b * L + l], ci = coli[b * L + l];
        float qv[8] = {q0.x, q0.y, q0.z, q0.w, q1.x, q1.y, q1.z, q1.w};
        float pv[8] = {p0.x, p0.y, p0.z, p0.w, p1.x, p1.y, p1.z, p1.w};
        #pragma unroll
        for (int k = 0; k < 8; ++k) {
            aq[k] += qv[k]; ap[k] += pv[k]; ab[k] += cj * pv[k]; aa[k] += ci * qv[k];
        }
    }
    const long o = ((long)c * B + b) * D + d0;
    *(float4*)(pq + o) = make_float4(aq[0], aq[1], aq[2], aq[3]);
    *(float4*)(pq + o + 4) = make_float4(aq[4], aq[5], aq[6], aq[7]);
    *(float4*)(pp + o) = make_float4(ap[0], ap[1], ap[2], ap[3]);
    *(float4*)(pp + o + 4) = make_float4(ap[4], ap[5], ap[6], ap[7]);
    *(float4*)(pb + o) = make_float4(ab[0], ab[1], ab[2], ab[3]);
    *(float4*)(pb + o + 4) = make_float4(ab[4], ab[5], ab[6], ab[7]);
    *(float4*)(pa + o) = make_float4(aa[0], aa[1], aa[2], aa[3]);
    *(float4*)(pa + o + 4) = make_float4(aa[4], aa[5], aa[6], aa[7]);
}

__global__ __launch_bounds__(256) void k_final2(const float* __restrict__ pq,
                                                const float* __restrict__ pp,
                                                const float* __restrict__ pb,
                                                const float* __restrict__ pa,
                                                const float* __restrict__ gp1,
                                                const float* __restrict__ gp2,
                                                float* __restrict__ out) {
    const int b = blockIdx.x, t = threadIdx.x;
    float acc = 0.f;
    for (int d = t; d < D; d += 256) {
        float sq = 0.f, sp_ = 0.f, sb = 0.f, sa = 0.f;
        #pragma unroll
        for (int c2 = 0; c2 < 16; ++c2) {
            long o = ((long)c2 * B + b) * D + d;
            sq += pq[o]; sp_ += pp[o]; sb += pb[o]; sa += pa[o];
        }
        float g1d = 0.f, g1D = 0.f, g2d = 0.f, g2D = 0.f;
        #pragma unroll
        for (int ec = 0; ec < 8; ++ec) {
            g1d += gp1[ec * 2048 + d];     g1D += gp1[ec * 2048 + D + d];
            g2d += gp2[ec * 2048 + d];     g2D += gp2[ec * 2048 + D + d];
        }
        acc += sq * g1d + sb * g1D + sp_ * g2d + sa * g2D;
    }
    #pragma unroll
    for (int o = 32; o; o >>= 1) acc += __shfl_xor(acc, o);
    __shared__ float red[4];
    const int wid = t >> 6, lane = t & 63;
    if (lane == 0) red[wid] = acc;
    __syncthreads();
    if (t == 0) out[b] = red[0] + red[1] + red[2] + red[3];
}

// ---------------------------------------------------------------------------
extern "C" void kernel_launch(void* const* d_in, const int* in_sizes, int n_in,
                              void* d_out, int out_size, void* d_ws, size_t ws_size,
                              hipStream_t stream) {
    const float* q  = (const float*)d_in[0];
    const float* p  = (const float*)d_in[1];
    const int*   qm = (const int*)d_in[2];
    const int*   pm = (const int*)d_in[3];
    const float* WF = (const float*)d_in[4];
    const float* WG = (const float*)d_in[5];
    const float* WH = (const float*)d_in[6];
    float* out = (float*)d_out;

    // Workspace layout (~72 MB)
    char* wsb = (char*)d_ws;
    short* T16   = (short*)(wsb);                   // 32 MB
    short* WFt16 = (short*)(wsb + (32l << 20));     // 2 MB
    short* G16   = (short*)(wsb + (34l << 20));     // 2 MB
    float* Gp    = (float*)(wsb + (36l << 20));     // 16 MB (dead after fold)
    float* E     = (float*)(wsb + (36l << 20));     // 16 MB (overlays Gp)
    float* st    = (float*)(wsb + (52l << 20));
    const int BL = B * L;
    float* impart = st;                  float* ispart = impart + B * 8 * 256;
    float* cjpart = ispart + B * 8 * 256;
    float* rmi  = cjpart + B * 8 * 256;  float* rsi  = rmi + BL;
    float* colj = rsi + BL;              float* coli = colj + BL;
    float* pq   = coli + BL;             float* pp   = pq + 16 * BD;
    float* pb   = pp + 16 * BD;          float* pa   = pb + 16 * BD;
    float* gp1  = pa + 16 * BD;          float* gp2  = gp1 + 8 * 2048;

    // prep: WF transpose | gp partials
    k_wfgp<<<1088, 256, 0, stream>>>(WF, WG, WH, WFt16, gp1, gp2);
    // gram partials: K-split 4 (z = K-chunk of 256, NT=4), 128x128 tiles
    k_gemm<2, 2, 4, 0, 0><<<256, 256, 0, stream>>>(
        (const char*)WFt16, 2048, 512, (const char*)WFt16, 2048, 512,
        256, 8, 64, 0, nullptr, Gp, 1024, 1l << 20);
    k_fold_g<<<1024, 256, 0, stream>>>(Gp, G16);
    // T = q @ G: A = q fp32 (in-staging cvt), B = G16. 256x256 tiles, NT=16.
    k_gemm<2, 4, 8, 1, 0><<<256, 512, 0, stream>>>(
        (const char*)q, 4096, 0, (const char*)G16, 2048, 0,
        1024, 4, 256, 1, T16, nullptr, 1024, 0);
    // E[b] = T_b @ p_b^T: A = T16, B = p fp32 (in-staging cvt). NT=16.
    k_gemm<2, 2, 4, 0, 1><<<256, 256, 0, stream>>>(
        (const char*)T16, 64l * 2048, 2048, (const char*)p, 64l * 4096, 4096,
        1024, 2, 4, 0, nullptr, E, 256, 65536);
    // softmax
    k_pass1<<<dim3(8, B), 256, 0, stream>>>(E, qm, pm, impart, ispart, cjpart);
    k_combine<<<B, 256, 0, stream>>>(impart, ispart, cjpart, rmi, rsi, colj);
    k_colsum_i<<<BL / 4, 256, 0, stream>>>(E, qm, pm, rmi, rsi, coli);
    // per-batch sums (fp32 q/p), 1024 blocks
    k_sums2<<<dim3(16, B), 128, 0, stream>>>(q, p, colj, coli, pq, pp, pb, pa);
    // final
    k_final2<<<B, 256, 0, stream>>>(pq, pp, pb, pa, gp1, gp2, out);
}